// Round 7
// baseline (295.819 us; speedup 1.0000x reference)
//
#include <hip/hip_runtime.h>
#include <hip/hip_cooperative_groups.h>
#include <stdint.h>

namespace cg = cooperative_groups;

#define B_   2
#define H_   12
#define S_   512
#define D_   64
#define ALL_ 768
#define NPAIR 78
#define NBLK 512

// d_out offsets (in floats), concatenated in reference return order
#define OFF_TN  0            // transformed_norm   [B,H,S]      12288
#define OFF_WN  12288        // weighted_norm      [B,H,S,S]    6291456
#define OFF_SWN 6303744      // summed_weighted_norm [B,S,S]    524288
#define OFF_T   6828032      // transformed        [B,H,S,ALL]  9437184

typedef short short4v __attribute__((ext_vector_type(4)));
typedef short short8v __attribute__((ext_vector_type(8)));
typedef float f32x4  __attribute__((ext_vector_type(4)));

// unique symmetric pair index (h1<=h2), p in [0,78)
__host__ __device__ constexpr int pairIdx(int h1, int h2) {
  return h1 * 12 - (h1 * (h1 - 1)) / 2 + (h2 - h1);
}

__device__ inline short f2bf(float x) {
  union { float f; uint32_t u; } c; c.f = x;
  uint32_t r = (c.u + 0x7FFFu + ((c.u >> 16) & 1u)) >> 16;
  return (short)r;
}

// ---------------------------------------------------------------------------
// Cooperative kernel, 512 blocks x 256 threads (2 blocks/CU — comfortably
// co-resident), three phases separated by grid.sync():
//  A: T = V @ W^T per head. 64x96 tiles -> 1536 tasks = 3/block.
//  B: Gram via mfma(x,x). 1024 (b,s) waves spread 2/block over all blocks.
//  C: WN = |p|*tn, SWN = sqrt(p^T G p). 512 tasks = 1/block.
// Frag layouts (validated r2-r5): A a[j]=A[m=l&15][k=lg*8+j];
// B b[j]=B[k][n=l&15]; C/D col=l&15, row=lg*4+r  [m89].
// ---------------------------------------------------------------------------
__global__ __launch_bounds__(256, 2) void fused(const float* __restrict__ P,
                                                const float* __restrict__ V,
                                                const float* __restrict__ W,
                                                float* __restrict__ out,
                                                float* __restrict__ GT) {
  __shared__ char Bb[96 * 128];    // [e-row][64 k] bf16, swizzled
  const int bid = blockIdx.x;
  const int tid = threadIdx.x;
  const int l = tid & 63, w = tid >> 6;
  const int lr = l & 15, lg = l >> 4;

  float* T   = out + OFF_T;
  float* TN  = out + OFF_TN;
  float* WN  = out + OFF_WN;
  float* SWN = out + OFF_SWN;

  // ---------------- Phase A ----------------
  for (int t = bid; t < 1536; t += NBLK) {
    const int h = t % 12;
    const int q = t / 12;
    const int et = q & 7, rt = q >> 3;

    if (t != bid) __syncthreads();   // Bb readers from previous task done

    // stage W tile: 96 e-rows x 16 float4-chunks = 1536 tasks (6/thread)
#pragma unroll
    for (int p = 0; p < 6; ++p) {
      int f = tid + (p << 8);        // 0..1535
      int row = f >> 4, c = f & 15;  // k = 4c
      int addr = ((row << 7) + (c << 3)) ^ ((row & 7) << 4);
      float4 wv = *(const float4*)&W[(et * 96 + row) * ALL_ + (h << 6) + (c << 2)];
      short4v wsv = { f2bf(wv.x), f2bf(wv.y), f2bf(wv.z), f2bf(wv.w) };
      *(short4v*)(Bb + addr) = wsv;
    }

    // A-fragments direct from global: lane reads V[row][ks*32+lg*8 .. +7]
    short8v a[2];
    {
      int row = (w << 4) + lr;
      int gr = (rt << 6) + row;
      int b = gr >> 9, s = gr & 511;
      const float* src = &V[(((b * H_ + h) << 9) + s) << 6];
#pragma unroll
      for (int ks = 0; ks < 2; ++ks) {
        float4 u0 = *(const float4*)(src + (ks << 5) + (lg << 3));
        float4 u1 = *(const float4*)(src + (ks << 5) + (lg << 3) + 4);
        a[ks] = (short8v){f2bf(u0.x), f2bf(u0.y), f2bf(u0.z), f2bf(u0.w),
                          f2bf(u1.x), f2bf(u1.y), f2bf(u1.z), f2bf(u1.w)};
      }
    }
    __syncthreads();

    f32x4 acc[6];
#pragma unroll
    for (int tn = 0; tn < 6; ++tn) acc[tn] = (f32x4){0.f, 0.f, 0.f, 0.f};

#pragma unroll
    for (int ks = 0; ks < 2; ++ks)
#pragma unroll
      for (int tn = 0; tn < 6; ++tn) {
        int row = (tn << 4) + lr;
        int addr = ((row << 7) + (ks << 6) + (lg << 4)) ^ ((row & 7) << 4);
        short8v bf = *(short8v*)(Bb + addr);
        acc[tn] = __builtin_amdgcn_mfma_f32_16x16x32_bf16(a[ks], bf, acc[tn], 0, 0, 0);
      }

    // epilogue: lane writes col (et*96 + lr + 16*tn), row (w*16 + lg*4 + r)
#pragma unroll
    for (int r = 0; r < 4; ++r) {
      int row = (w << 4) + (lg << 2) + r;
      int gr = (rt << 6) + row;
      int b = gr >> 9, s = gr & 511;
      float* dst = &T[(((b * H_ + h) << 9) + s) * ALL_ + et * 96 + lr];
#pragma unroll
      for (int tn = 0; tn < 6; ++tn)
        dst[tn << 4] = acc[tn][r];
    }
  }

  __threadfence();
  cg::this_grid().sync();

  // ---------------- Phase B ----------------
  if ((w & 1) == 0) {                // waves 0,2 of each block
    const int bs = (bid << 1) + (w >> 1);   // 0..1023
    const int b = bs >> 9, s = bs & 511;
    const int col = lr;
    const float* rowp = T + (((b * H_ + col) << 9) + s) * ALL_;  // h = col
    const bool act = col < 12;

    f32x4 acc = (f32x4){0.f, 0.f, 0.f, 0.f};
#pragma unroll
    for (int kk = 0; kk < 24; ++kk) {
      const int e = (kk << 5) + (lg << 3);
      short8v x = (short8v){0, 0, 0, 0, 0, 0, 0, 0};
      if (act) {
        float4 u0 = *(const float4*)(rowp + e);
        float4 u1 = *(const float4*)(rowp + e + 4);
        x = (short8v){f2bf(u0.x), f2bf(u0.y), f2bf(u0.z), f2bf(u0.w),
                      f2bf(u1.x), f2bf(u1.y), f2bf(u1.z), f2bf(u1.w)};
      }
      acc = __builtin_amdgcn_mfma_f32_16x16x32_bf16(x, x, acc, 0, 0, 0);
    }

#pragma unroll
    for (int r = 0; r < 4; ++r) {
      const int rw = (lg << 2) + r;   // Gram row
      if (col < 12 && rw <= col) {
        const int p = rw * 12 - (rw * (rw - 1)) / 2 + (col - rw);
        GT[(b * NPAIR + p) * S_ + s] = acc[r];
        if (rw == col) TN[(b * H_ + col) * S_ + s] = sqrtf(acc[r]);
      }
    }
  }

  __threadfence();
  cg::this_grid().sync();

  // ---------------- Phase C ----------------
  {
    const int st = bid & 7, kt = (bid >> 3) & 31, b = bid >> 8;
    const int sl = tid & 63, kq = tid >> 6;
    const int s = (st << 6) + sl;

    float g[NPAIR];
#pragma unroll
    for (int p = 0; p < NPAIR; ++p)
      g[p] = GT[(b * NPAIR + p) * S_ + s];
    float tn[12];
#pragma unroll
    for (int h = 0; h < 12; ++h)
      tn[h] = sqrtf(g[pairIdx(h, h)]);

#pragma unroll
    for (int half = 0; half < 2; ++half) {
      float pv[2][12];
#pragma unroll
      for (int kp = 0; kp < 2; ++kp) {
        const int k = (kt << 4) + ((half * 2 + kp) << 2) + kq;
#pragma unroll
        for (int h = 0; h < 12; ++h)
          pv[kp][h] = P[(((b * H_ + h) << 9) + k) * S_ + s];
      }
#pragma unroll
      for (int kp = 0; kp < 2; ++kp) {
        const int k = (kt << 4) + ((half * 2 + kp) << 2) + kq;
#pragma unroll
        for (int h = 0; h < 12; ++h) {
          const int idx = (((b * H_ + h) << 9) + k) * S_ + s;
          WN[idx] = fabsf(pv[kp][h]) * tn[h];
        }
        float qv = 0.f;
#pragma unroll
        for (int h1 = 0; h1 < 12; ++h1) {
          qv = fmaf(pv[kp][h1] * pv[kp][h1], g[pairIdx(h1, h1)], qv);
#pragma unroll
          for (int h2 = h1 + 1; h2 < 12; ++h2)
            qv = fmaf(2.f * pv[kp][h1] * pv[kp][h2], g[pairIdx(h1, h2)], qv);
        }
        SWN[((b << 9) + k) * S_ + s] = sqrtf(fmaxf(qv, 0.f));
      }
    }
  }
}

// ===========================================================================
// Fallback path: the r5-validated 3-kernel pipeline (39.8 us), launched only
// if the cooperative launch is rejected (deterministic per-config).
// ===========================================================================
__global__ __launch_bounds__(128) void kernelA(const float* __restrict__ V,
                                               const float* __restrict__ W,
                                               float* __restrict__ T) {
  __shared__ char Bb[128 * 128];   // [e][64 k] bf16, swizzled
  const int tid = threadIdx.x;
  const int et = blockIdx.x, rt = blockIdx.y, h = blockIdx.z;

#pragma unroll
  for (int p = 0; p < 16; ++p) {
    int f = tid + (p << 7);          // 0..2047
    int row = f >> 4, c = f & 15;    // k = 4c
    int addr = ((row << 7) + (c << 3)) ^ ((row & 7) << 4);
    float4 wv = *(const float4*)&W[((et << 7) + row) * ALL_ + (h << 6) + (c << 2)];
    short4v wsv = { f2bf(wv.x), f2bf(wv.y), f2bf(wv.z), f2bf(wv.w) };
    *(short4v*)(Bb + addr) = wsv;
  }

  const int l = tid & 63, w = tid >> 6;
  const int lr = l & 15, lg = l >> 4;

  short8v a[2][2];  // [ks][tm]
#pragma unroll
  for (int ks = 0; ks < 2; ++ks)
#pragma unroll
    for (int tm = 0; tm < 2; ++tm) {
      int row = (w << 5) + (tm << 4) + lr;
      int gr = (rt << 6) + row;
      int b = gr >> 9, s = gr & 511;
      const float* src = &V[((((b * H_ + h) << 9) + s) << 6) + (ks << 5) + (lg << 3)];
      float4 u0 = *(const float4*)src;
      float4 u1 = *(const float4*)(src + 4);
      a[ks][tm] = (short8v){f2bf(u0.x), f2bf(u0.y), f2bf(u0.z), f2bf(u0.w),
                            f2bf(u1.x), f2bf(u1.y), f2bf(u1.z), f2bf(u1.w)};
    }
  __syncthreads();

  f32x4 acc[2][8];
#pragma unroll
  for (int i = 0; i < 2; ++i)
#pragma unroll
    for (int j = 0; j < 8; ++j) acc[i][j] = (f32x4){0.f, 0.f, 0.f, 0.f};

#pragma unroll
  for (int ks = 0; ks < 2; ++ks)
#pragma unroll
    for (int tn = 0; tn < 8; ++tn) {
      int row = (tn << 4) + lr;
      int addr = ((row << 7) + (ks << 6) + (lg << 4)) ^ ((row & 7) << 4);
      short8v bf = *(short8v*)(Bb + addr);
      acc[0][tn] = __builtin_amdgcn_mfma_f32_16x16x32_bf16(a[ks][0], bf, acc[0][tn], 0, 0, 0);
      acc[1][tn] = __builtin_amdgcn_mfma_f32_16x16x32_bf16(a[ks][1], bf, acc[1][tn], 0, 0, 0);
    }

#pragma unroll
  for (int tm = 0; tm < 2; ++tm)
#pragma unroll
    for (int r = 0; r < 4; ++r) {
      int row = (w << 5) + (tm << 4) + (lg << 2) + r;
      int gr = (rt << 6) + row;
      int b = gr >> 9, s = gr & 511;
      float* dst = &T[(((b * H_ + h) << 9) + s) * ALL_ + (et << 7) + lr];
#pragma unroll
      for (int tn = 0; tn < 8; ++tn)
        dst[tn << 4] = acc[tm][tn][r];
    }
}

__global__ __launch_bounds__(256) void kernelB(const float* __restrict__ T,
                                               float* __restrict__ TN,
                                               float* __restrict__ GT) {
  const int tid = threadIdx.x;
  const int w = tid >> 6, l = tid & 63;
  const int bs = (blockIdx.x << 2) + w;
  const int b = bs >> 9, s = bs & 511;
  const int col = l & 15, lg = l >> 4;

  const float* rowp = T + (((b * H_ + col) << 9) + s) * ALL_;  // h = col
  const bool act = col < 12;

  f32x4 acc = (f32x4){0.f, 0.f, 0.f, 0.f};
#pragma unroll
  for (int kk = 0; kk < 24; ++kk) {
    const int e = (kk << 5) + (lg << 3);
    short8v x = (short8v){0, 0, 0, 0, 0, 0, 0, 0};
    if (act) {
      float4 u0 = *(const float4*)(rowp + e);
      float4 u1 = *(const float4*)(rowp + e + 4);
      x = (short8v){f2bf(u0.x), f2bf(u0.y), f2bf(u0.z), f2bf(u0.w),
                    f2bf(u1.x), f2bf(u1.y), f2bf(u1.z), f2bf(u1.w)};
    }
    acc = __builtin_amdgcn_mfma_f32_16x16x32_bf16(x, x, acc, 0, 0, 0);
  }

#pragma unroll
  for (int r = 0; r < 4; ++r) {
    const int rw = (lg << 2) + r;     // Gram row
    const float v = acc[r];
    if (col < 12 && rw <= col) {
      const int p = rw * 12 - (rw * (rw - 1)) / 2 + (col - rw);
      GT[(b * NPAIR + p) * S_ + s] = v;
      if (rw == col) TN[(b * H_ + col) * S_ + s] = sqrtf(v);
    }
  }
}

__global__ __launch_bounds__(256) void kernelC(const float* __restrict__ P,
                                               const float* __restrict__ GT,
                                               float* __restrict__ WN,
                                               float* __restrict__ SWN) {
  const int tid = threadIdx.x;
  const int st = blockIdx.x, kt = blockIdx.y, b = blockIdx.z;
  const int sl = tid & 63, kq = tid >> 6;
  const int s = (st << 6) + sl;

  float g[NPAIR];
#pragma unroll
  for (int p = 0; p < NPAIR; ++p)
    g[p] = GT[(b * NPAIR + p) * S_ + s];
  float tn[12];
#pragma unroll
  for (int h = 0; h < 12; ++h)
    tn[h] = sqrtf(g[pairIdx(h, h)]);

  float pv[4][12];
#pragma unroll
  for (int kp = 0; kp < 4; ++kp) {
    const int k = (kt << 4) + (kp << 2) + kq;
#pragma unroll
    for (int h = 0; h < 12; ++h)
      pv[kp][h] = P[(((b * H_ + h) << 9) + k) * S_ + s];
  }

#pragma unroll
  for (int kp = 0; kp < 4; ++kp) {
    const int k = (kt << 4) + (kp << 2) + kq;
#pragma unroll
    for (int h = 0; h < 12; ++h) {
      const int idx = (((b * H_ + h) << 9) + k) * S_ + s;
      WN[idx] = fabsf(pv[kp][h]) * tn[h];
    }
    float q = 0.f;
#pragma unroll
    for (int h1 = 0; h1 < 12; ++h1) {
      q = fmaf(pv[kp][h1] * pv[kp][h1], g[pairIdx(h1, h1)], q);
#pragma unroll
      for (int h2 = h1 + 1; h2 < 12; ++h2)
        q = fmaf(2.f * pv[kp][h1] * pv[kp][h2], g[pairIdx(h1, h2)], q);
    }
    SWN[((b << 9) + k) * S_ + s] = sqrtf(fmaxf(q, 0.f));
  }
}

// ---------------------------------------------------------------------------
extern "C" void kernel_launch(void* const* d_in, const int* in_sizes, int n_in,
                              void* d_out, int out_size, void* d_ws, size_t ws_size,
                              hipStream_t stream) {
  const float* P = (const float*)d_in[1];
  const float* V = (const float*)d_in[2];
  const float* W = (const float*)d_in[3];
  float* out = (float*)d_out;
  float* GT = (float*)d_ws;  // [B][78][S] = 319,488 bytes

  void* args[] = {(void*)&P, (void*)&V, (void*)&W, (void*)&out, (void*)&GT};
  hipError_t err = hipLaunchCooperativeKernel((const void*)fused, dim3(NBLK),
                                              dim3(256), args, 0, stream);
  if (err != hipSuccess) {
    // deterministic fallback: r5-validated 3-kernel path
    kernelA<<<dim3(6, 16, 12), 128, 0, stream>>>(V, W, out + OFF_T);
    kernelB<<<dim3(256), 256, 0, stream>>>(out + OFF_T, out + OFF_TN, GT);
    kernelC<<<dim3(8, 32, 2), 256, 0, stream>>>(P, GT, out + OFF_WN, out + OFF_SWN);
  }
}

// Round 8
// 35.458 us; speedup vs baseline: 8.3429x; 8.3429x over previous
//
#include <hip/hip_runtime.h>
#include <stdint.h>

#define B_   2
#define H_   12
#define S_   512
#define D_   64
#define ALL_ 768
#define NPAIR 78

// d_out offsets (in floats), concatenated in reference return order
#define OFF_TN  0            // transformed_norm   [B,H,S]      12288
#define OFF_WN  12288        // weighted_norm      [B,H,S,S]    6291456
#define OFF_SWN 6303744      // summed_weighted_norm [B,S,S]    524288
#define OFF_T   6828032      // transformed        [B,H,S,ALL]  9437184

typedef short short4v __attribute__((ext_vector_type(4)));
typedef short short8v __attribute__((ext_vector_type(8)));
typedef float f32x4  __attribute__((ext_vector_type(4)));

// unique symmetric pair index (h1<=h2), p in [0,78)
__host__ __device__ constexpr int pairIdx(int h1, int h2) {
  return h1 * 12 - (h1 * (h1 - 1)) / 2 + (h2 - h1);
}

__device__ inline short f2bf(float x) {
  union { float f; uint32_t u; } c; c.f = x;
  uint32_t r = (c.u + 0x7FFFu + ((c.u >> 16) & 1u)) >> 16;
  return (short)r;
}

// ---------------------------------------------------------------------------
// Kernel A (bf16 MFMA, validated r5): T[b,h,s,e] = sum_d V[b,h,s,d]*W[e,h*64+d]
// tile 64 rows x 128 e, K=64 (2 MFMA k-steps), block 128 (2 waves),
// grid (6 et, 16 rt, 12 h) = 1152. A-frags direct from global; W staged
// f32->bf16 in LDS with XOR swizzle byte ^= (row&7)<<4.
// Frag layouts: A a[j]=A[m=l&15][k=lg*8+j]; B b[j]=B[k][n=l&15];
// C/D col=l&15, row=lg*4+r  [m89].
// ---------------------------------------------------------------------------
__global__ __launch_bounds__(128) void kernelA(const float* __restrict__ V,
                                               const float* __restrict__ W,
                                               float* __restrict__ T) {
  __shared__ char Bb[128 * 128];   // [e][64 k] bf16, swizzled
  const int tid = threadIdx.x;
  const int et = blockIdx.x, rt = blockIdx.y, h = blockIdx.z;

#pragma unroll
  for (int p = 0; p < 16; ++p) {
    int f = tid + (p << 7);          // 0..2047
    int row = f >> 4, c = f & 15;    // k = 4c
    int addr = ((row << 7) + (c << 3)) ^ ((row & 7) << 4);
    float4 wv = *(const float4*)&W[((et << 7) + row) * ALL_ + (h << 6) + (c << 2)];
    short4v wsv = { f2bf(wv.x), f2bf(wv.y), f2bf(wv.z), f2bf(wv.w) };
    *(short4v*)(Bb + addr) = wsv;
  }

  const int l = tid & 63, w = tid >> 6;
  const int lr = l & 15, lg = l >> 4;

  short8v a[2][2];  // [ks][tm]
#pragma unroll
  for (int ks = 0; ks < 2; ++ks)
#pragma unroll
    for (int tm = 0; tm < 2; ++tm) {
      int row = (w << 5) + (tm << 4) + lr;
      int gr = (rt << 6) + row;
      int b = gr >> 9, s = gr & 511;
      const float* src = &V[((((b * H_ + h) << 9) + s) << 6) + (ks << 5) + (lg << 3)];
      float4 u0 = *(const float4*)src;
      float4 u1 = *(const float4*)(src + 4);
      a[ks][tm] = (short8v){f2bf(u0.x), f2bf(u0.y), f2bf(u0.z), f2bf(u0.w),
                            f2bf(u1.x), f2bf(u1.y), f2bf(u1.z), f2bf(u1.w)};
    }
  __syncthreads();

  f32x4 acc[2][8];
#pragma unroll
  for (int i = 0; i < 2; ++i)
#pragma unroll
    for (int j = 0; j < 8; ++j) acc[i][j] = (f32x4){0.f, 0.f, 0.f, 0.f};

#pragma unroll
  for (int ks = 0; ks < 2; ++ks)
#pragma unroll
    for (int tn = 0; tn < 8; ++tn) {
      int row = (tn << 4) + lr;
      int addr = ((row << 7) + (ks << 6) + (lg << 4)) ^ ((row & 7) << 4);
      short8v bf = *(short8v*)(Bb + addr);
      acc[0][tn] = __builtin_amdgcn_mfma_f32_16x16x32_bf16(a[ks][0], bf, acc[0][tn], 0, 0, 0);
      acc[1][tn] = __builtin_amdgcn_mfma_f32_16x16x32_bf16(a[ks][1], bf, acc[1][tn], 0, 0, 0);
    }

#pragma unroll
  for (int tm = 0; tm < 2; ++tm)
#pragma unroll
    for (int r = 0; r < 4; ++r) {
      int row = (w << 5) + (tm << 4) + (lg << 2) + r;
      int gr = (rt << 6) + row;
      int b = gr >> 9, s = gr & 511;
      float* dst = &T[(((b * H_ + h) << 9) + s) * ALL_ + (et << 7) + lr];
#pragma unroll
      for (int tn = 0; tn < 8; ++tn)
        dst[tn << 4] = acc[tm][tn][r];
    }
}

// ---------------------------------------------------------------------------
// Kernel B v2 (MFMA Gram, 4-way split): one BLOCK per (b,s) = 1024 blocks,
// 4 waves. Wave w covers e in [192w, 192w+192) -> 6 mfma(x,x) k-steps
// (B-frag of X^T == A-frag of X). Partial Grams reduced via 4KB LDS.
// 16 waves/CU (vs 4 in r5) and a 4x shorter dependent MFMA chain.
// ---------------------------------------------------------------------------
__global__ __launch_bounds__(256) void kernelB(const float* __restrict__ T,
                                               float* __restrict__ TN,
                                               float* __restrict__ GT) {
  __shared__ float Ls[4][64][4];
  const int tid = threadIdx.x;
  const int w = tid >> 6, l = tid & 63;
  const int bs = blockIdx.x;
  const int b = bs >> 9, s = bs & 511;
  const int col = l & 15, lg = l >> 4;

  const float* rowp = T + (((b * H_ + col) << 9) + s) * ALL_;  // h = col
  const bool act = col < 12;

  f32x4 acc = (f32x4){0.f, 0.f, 0.f, 0.f};
#pragma unroll
  for (int kk = 0; kk < 6; ++kk) {
    const int e = ((w * 6 + kk) << 5) + (lg << 3);
    short8v x = (short8v){0, 0, 0, 0, 0, 0, 0, 0};
    if (act) {
      float4 u0 = *(const float4*)(rowp + e);
      float4 u1 = *(const float4*)(rowp + e + 4);
      x = (short8v){f2bf(u0.x), f2bf(u0.y), f2bf(u0.z), f2bf(u0.w),
                    f2bf(u1.x), f2bf(u1.y), f2bf(u1.z), f2bf(u1.w)};
    }
    acc = __builtin_amdgcn_mfma_f32_16x16x32_bf16(x, x, acc, 0, 0, 0);
  }

  *(f32x4*)&Ls[w][l][0] = acc;
  __syncthreads();

  if (w == 0) {
#pragma unroll
    for (int r = 0; r < 4; ++r) {
      const int rw = (lg << 2) + r;     // Gram row
      if (col < 12 && rw <= col) {
        const float v = Ls[0][l][r] + Ls[1][l][r] + Ls[2][l][r] + Ls[3][l][r];
        const int p = rw * 12 - (rw * (rw - 1)) / 2 + (col - rw);
        GT[(b * NPAIR + p) * S_ + s] = v;
        if (rw == col) TN[(b * H_ + col) * S_ + s] = sqrtf(v);
      }
    }
  }
}

// ---------------------------------------------------------------------------
// Kernel C (validated r5): weighted_norm = |p|*tn; SWN = sqrt(p^T G p).
// grid (8 st, 32 kt, 2 b) = 512 blocks. g[78] in registers, 16 k reuse,
// all 48 P-loads batched for MLP.
// ---------------------------------------------------------------------------
__global__ __launch_bounds__(256) void kernelC(const float* __restrict__ P,
                                               const float* __restrict__ GT,
                                               float* __restrict__ WN,
                                               float* __restrict__ SWN) {
  const int tid = threadIdx.x;
  const int st = blockIdx.x, kt = blockIdx.y, b = blockIdx.z;
  const int sl = tid & 63, kq = tid >> 6;
  const int s = (st << 6) + sl;

  float g[NPAIR];
#pragma unroll
  for (int p = 0; p < NPAIR; ++p)
    g[p] = GT[(b * NPAIR + p) * S_ + s];
  float tn[12];
#pragma unroll
  for (int h = 0; h < 12; ++h)
    tn[h] = sqrtf(g[pairIdx(h, h)]);

  float pv[4][12];
#pragma unroll
  for (int kp = 0; kp < 4; ++kp) {
    const int k = (kt << 4) + (kp << 2) + kq;
#pragma unroll
    for (int h = 0; h < 12; ++h)
      pv[kp][h] = P[(((b * H_ + h) << 9) + k) * S_ + s];
  }

#pragma unroll
  for (int kp = 0; kp < 4; ++kp) {
    const int k = (kt << 4) + (kp << 2) + kq;
#pragma unroll
    for (int h = 0; h < 12; ++h) {
      const int idx = (((b * H_ + h) << 9) + k) * S_ + s;
      WN[idx] = fabsf(pv[kp][h]) * tn[h];
    }
    float q = 0.f;
#pragma unroll
    for (int h1 = 0; h1 < 12; ++h1) {
      q = fmaf(pv[kp][h1] * pv[kp][h1], g[pairIdx(h1, h1)], q);
#pragma unroll
      for (int h2 = h1 + 1; h2 < 12; ++h2)
        q = fmaf(2.f * pv[kp][h1] * pv[kp][h2], g[pairIdx(h1, h2)], q);
    }
    SWN[((b << 9) + k) * S_ + s] = sqrtf(fmaxf(q, 0.f));
  }
}

// ---------------------------------------------------------------------------
extern "C" void kernel_launch(void* const* d_in, const int* in_sizes, int n_in,
                              void* d_out, int out_size, void* d_ws, size_t ws_size,
                              hipStream_t stream) {
  const float* P = (const float*)d_in[1];
  const float* V = (const float*)d_in[2];
  const float* W = (const float*)d_in[3];
  float* out = (float*)d_out;
  float* GT = (float*)d_ws;  // [B][78][S] = 319,488 bytes

  kernelA<<<dim3(6, 16, 12), 128, 0, stream>>>(V, W, out + OFF_T);
  kernelB<<<dim3(1024), 256, 0, stream>>>(out + OFF_T, out + OFF_TN, GT);
  kernelC<<<dim3(8, 32, 2), 256, 0, stream>>>(P, GT, out + OFF_WN, out + OFF_SWN);
}

// Round 9
// 35.325 us; speedup vs baseline: 8.3742x; 1.0038x over previous
//
#include <hip/hip_runtime.h>
#include <stdint.h>

#define B_   2
#define H_   12
#define S_   512
#define D_   64
#define ALL_ 768
#define NPAIR 78

// d_out offsets (in floats), concatenated in reference return order
#define OFF_TN  0            // transformed_norm   [B,H,S]      12288
#define OFF_WN  12288        // weighted_norm      [B,H,S,S]    6291456
#define OFF_SWN 6303744      // summed_weighted_norm [B,S,S]    524288
#define OFF_T   6828032      // transformed        [B,H,S,ALL]  9437184

typedef short short4v __attribute__((ext_vector_type(4)));
typedef short short8v __attribute__((ext_vector_type(8)));
typedef float f32x4  __attribute__((ext_vector_type(4)));

// unique symmetric pair index (h1<=h2), p in [0,78)
__host__ __device__ constexpr int pairIdx(int h1, int h2) {
  return h1 * 12 - (h1 * (h1 - 1)) / 2 + (h2 - h1);
}

__device__ inline short f2bf(float x) {
  union { float f; uint32_t u; } c; c.f = x;
  uint32_t r = (c.u + 0x7FFFu + ((c.u >> 16) & 1u)) >> 16;
  return (short)r;
}

// ---------------------------------------------------------------------------
// Kernel A (bf16 MFMA): T[b,h,s,e] = sum_d V[b,h,s,d]*W[e,h*64+d]
// tile 64 rows x 128 e, K=64, block 256 (4 waves; wave w covers rows
// 16w..16w+15 -> 16 MFMAs/wave), grid (6 et, 16 rt, 12 h) = 1152
// -> 18 waves/CU (was 9). W staged f32->bf16 in LDS, XOR swizzle
// byte ^= (row&7)<<4; A-frags direct from global.
// Frag layouts (validated r2-r8): A a[j]=A[m=l&15][k=lg*8+j];
// B b[j]=B[k][n=l&15]; C/D col=l&15, row=lg*4+r  [m89].
// ---------------------------------------------------------------------------
__global__ __launch_bounds__(256) void kernelA(const float* __restrict__ V,
                                               const float* __restrict__ W,
                                               float* __restrict__ T) {
  __shared__ char Bb[128 * 128];   // [e][64 k] bf16, swizzled
  const int tid = threadIdx.x;
  const int et = blockIdx.x, rt = blockIdx.y, h = blockIdx.z;

  // stage W: 128 e-rows x 16 float4-chunks = 2048 tasks (8/thread)
#pragma unroll
  for (int p = 0; p < 8; ++p) {
    int f = tid + (p << 8);          // 0..2047
    int row = f >> 4, c = f & 15;    // k = 4c
    int addr = ((row << 7) + (c << 3)) ^ ((row & 7) << 4);
    float4 wv = *(const float4*)&W[((et << 7) + row) * ALL_ + (h << 6) + (c << 2)];
    short4v wsv = { f2bf(wv.x), f2bf(wv.y), f2bf(wv.z), f2bf(wv.w) };
    *(short4v*)(Bb + addr) = wsv;
  }

  const int l = tid & 63, w = tid >> 6;
  const int lr = l & 15, lg = l >> 4;

  // A-fragments direct from global: lane reads V[row][ks*32 + lg*8 .. +7]
  short8v a[2];
  {
    int row = (w << 4) + lr;
    int gr = (rt << 6) + row;
    int b = gr >> 9, s = gr & 511;
    const float* src = &V[(((b * H_ + h) << 9) + s) << 6];
#pragma unroll
    for (int ks = 0; ks < 2; ++ks) {
      float4 u0 = *(const float4*)(src + (ks << 5) + (lg << 3));
      float4 u1 = *(const float4*)(src + (ks << 5) + (lg << 3) + 4);
      a[ks] = (short8v){f2bf(u0.x), f2bf(u0.y), f2bf(u0.z), f2bf(u0.w),
                        f2bf(u1.x), f2bf(u1.y), f2bf(u1.z), f2bf(u1.w)};
    }
  }
  __syncthreads();

  f32x4 acc[8];
#pragma unroll
  for (int j = 0; j < 8; ++j) acc[j] = (f32x4){0.f, 0.f, 0.f, 0.f};

#pragma unroll
  for (int ks = 0; ks < 2; ++ks)
#pragma unroll
    for (int tn = 0; tn < 8; ++tn) {
      int row = (tn << 4) + lr;
      int addr = ((row << 7) + (ks << 6) + (lg << 4)) ^ ((row & 7) << 4);
      short8v bf = *(short8v*)(Bb + addr);
      acc[tn] = __builtin_amdgcn_mfma_f32_16x16x32_bf16(a[ks], bf, acc[tn], 0, 0, 0);
    }

  // epilogue: lane writes col (et*128 + lr + 16*tn), row (w*16 + lg*4 + r)
#pragma unroll
  for (int r = 0; r < 4; ++r) {
    int row = (w << 4) + (lg << 2) + r;
    int gr = (rt << 6) + row;
    int b = gr >> 9, s = gr & 511;
    float* dst = &T[(((b * H_ + h) << 9) + s) * ALL_ + (et << 7) + lr];
#pragma unroll
    for (int tn = 0; tn < 8; ++tn)
      dst[tn << 4] = acc[tn][r];
  }
}

// ---------------------------------------------------------------------------
// Kernel B (MFMA Gram, 4-way split, validated r8): one block per (b,s),
// 4 waves; wave w covers e in [192w, 192w+192) -> 6 mfma(x,x) k-steps
// (B-frag of X^T == A-frag of X). Partial Grams reduced via 4KB LDS.
// ---------------------------------------------------------------------------
__global__ __launch_bounds__(256) void kernelB(const float* __restrict__ T,
                                               float* __restrict__ TN,
                                               float* __restrict__ GT) {
  __shared__ float Ls[4][64][4];
  const int tid = threadIdx.x;
  const int w = tid >> 6, l = tid & 63;
  const int bs = blockIdx.x;
  const int b = bs >> 9, s = bs & 511;
  const int col = l & 15, lg = l >> 4;

  const float* rowp = T + (((b * H_ + col) << 9) + s) * ALL_;  // h = col
  const bool act = col < 12;

  f32x4 acc = (f32x4){0.f, 0.f, 0.f, 0.f};
#pragma unroll
  for (int kk = 0; kk < 6; ++kk) {
    const int e = ((w * 6 + kk) << 5) + (lg << 3);
    short8v x = (short8v){0, 0, 0, 0, 0, 0, 0, 0};
    if (act) {
      float4 u0 = *(const float4*)(rowp + e);
      float4 u1 = *(const float4*)(rowp + e + 4);
      x = (short8v){f2bf(u0.x), f2bf(u0.y), f2bf(u0.z), f2bf(u0.w),
                    f2bf(u1.x), f2bf(u1.y), f2bf(u1.z), f2bf(u1.w)};
    }
    acc = __builtin_amdgcn_mfma_f32_16x16x32_bf16(x, x, acc, 0, 0, 0);
  }

  *(f32x4*)&Ls[w][l][0] = acc;
  __syncthreads();

  if (w == 0) {
#pragma unroll
    for (int r = 0; r < 4; ++r) {
      const int rw = (lg << 2) + r;     // Gram row
      if (col < 12 && rw <= col) {
        const float v = Ls[0][l][r] + Ls[1][l][r] + Ls[2][l][r] + Ls[3][l][r];
        const int p = rw * 12 - (rw * (rw - 1)) / 2 + (col - rw);
        GT[(b * NPAIR + p) * S_ + s] = v;
        if (rw == col) TN[(b * H_ + col) * S_ + s] = sqrtf(v);
      }
    }
  }
}

// ---------------------------------------------------------------------------
// Kernel C: weighted_norm = |p|*tn; SWN = sqrt(p^T G p).
// grid (8 st, 64 kt, 2 b) = 1024 blocks (4/CU, 16 waves/CU — was 8).
// Each block: 64 s x 8 k. g[78] in registers; both kp batches' P-loads
// issued before compute.
// ---------------------------------------------------------------------------
__global__ __launch_bounds__(256) void kernelC(const float* __restrict__ P,
                                               const float* __restrict__ GT,
                                               float* __restrict__ WN,
                                               float* __restrict__ SWN) {
  const int tid = threadIdx.x;
  const int st = blockIdx.x, kt = blockIdx.y, b = blockIdx.z;
  const int sl = tid & 63, kq = tid >> 6;
  const int s = (st << 6) + sl;

  float g[NPAIR];
#pragma unroll
  for (int p = 0; p < NPAIR; ++p)
    g[p] = GT[(b * NPAIR + p) * S_ + s];
  float tn[12];
#pragma unroll
  for (int h = 0; h < 12; ++h)
    tn[h] = sqrtf(g[pairIdx(h, h)]);

  float pv[2][12];
#pragma unroll
  for (int kp = 0; kp < 2; ++kp) {
    const int k = (kt << 3) + (kp << 2) + kq;
#pragma unroll
    for (int h = 0; h < 12; ++h)
      pv[kp][h] = P[(((b * H_ + h) << 9) + k) * S_ + s];
  }

#pragma unroll
  for (int kp = 0; kp < 2; ++kp) {
    const int k = (kt << 3) + (kp << 2) + kq;
#pragma unroll
    for (int h = 0; h < 12; ++h) {
      const int idx = (((b * H_ + h) << 9) + k) * S_ + s;
      WN[idx] = fabsf(pv[kp][h]) * tn[h];
    }
    float q = 0.f;
#pragma unroll
    for (int h1 = 0; h1 < 12; ++h1) {
      q = fmaf(pv[kp][h1] * pv[kp][h1], g[pairIdx(h1, h1)], q);
#pragma unroll
      for (int h2 = h1 + 1; h2 < 12; ++h2)
        q = fmaf(2.f * pv[kp][h1] * pv[kp][h2], g[pairIdx(h1, h2)], q);
    }
    SWN[((b << 9) + k) * S_ + s] = sqrtf(fmaxf(q, 0.f));
  }
}

// ---------------------------------------------------------------------------
extern "C" void kernel_launch(void* const* d_in, const int* in_sizes, int n_in,
                              void* d_out, int out_size, void* d_ws, size_t ws_size,
                              hipStream_t stream) {
  const float* P = (const float*)d_in[1];
  const float* V = (const float*)d_in[2];
  const float* W = (const float*)d_in[3];
  float* out = (float*)d_out;
  float* GT = (float*)d_ws;  // [B][78][S] = 319,488 bytes

  kernelA<<<dim3(6, 16, 12), 256, 0, stream>>>(V, W, out + OFF_T);
  kernelB<<<dim3(1024), 256, 0, stream>>>(out + OFF_T, out + OFF_TN, GT);
  kernelC<<<dim3(8, 64, 2), 256, 0, stream>>>(P, GT, out + OFF_WN, out + OFF_SWN);
}